// Round 5
// baseline (110.662 us; speedup 1.0000x reference)
//
#include <hip/hip_runtime.h>

#define IMG_H 256
#define IMG_W 256
#define TW 64
#define TH 16
#define HR 22     // TH + 6 halo rows
#define HSTR4 65  // hA row stride in float4 units (65 mod 8 = 1)

// bit-swap column permutation (involution): conflict-free b128 writes (phase 1)
// and b128 reads (phase 2) at float4 granularity. Verified R4: 15.7M -> 2.9M.
__device__ __forceinline__ int cpos(int c) { return ((c & 7) << 3) | (c >> 3); }

// Gaussian 7-tap, f64-derived f32 constants (matches numpy f32 recipe to ~1e-7 rel)
#define G0 0.03663285f
#define G1 0.11128076f
#define G2 0.21674532f
#define G3 0.27068216f

// Fused SSIM, horizontal-first, 4-field algebra:
// SSIM needs only smoothed(x), smoothed(y), smoothed(x^2+y^2), smoothed(x*y)
// (sigma1_sq and sigma2_sq never appear separately) -> one float4 per pixel.
//  phase 1: 176 tasks (22 halo rows x 8 groups) compute 8 h-filtered float4
//           outputs each, directly from global (4 aligned float4 loads/img).
//  phase 2: lane=column vertical 7-tap (10 shared taps -> 4 rows/thread),
//           SSIM map, block reduction.
__global__ __launch_bounds__(256) void ssim_tile_kernel(
    const float* __restrict__ x, const float* __restrict__ y,
    float* __restrict__ partial) {
    __shared__ float4 hA[HR][HSTR4];   // hx, hy, h(x^2+y^2), h(x*y), cols permuted
    __shared__ float  wsum[4];

    const int tid = threadIdx.x;
    const int bx = blockIdx.x, by = blockIdx.y, plane = blockIdx.z;
    const int r0 = by * TH;
    const int c0 = bx * TW;
    const size_t base = (size_t)plane * (IMG_H * IMG_W);

    const float g[7] = {G0, G1, G2, G3, G2, G1, G0};

    // ---------------- Phase 1: horizontal pass ----------------
    if (tid < HR * 8) {
        const int rr = tid >> 3;          // halo row 0..21
        const int k  = tid & 7;           // col group -> outputs 8k..8k+7
        const int gr = r0 - 3 + rr;       // global row
        const int gc0 = c0 + 8 * k - 3;   // first input col (14 inputs gc0..gc0+13)

        float xin[16], yin[16];
        const bool row_ok = ((unsigned)gr < IMG_H);
        const bool col_interior = (bx > 0) & (bx < 3);

        if (row_ok & col_interior) {
            // (gc0-1) % 4 == 0: 4 aligned float4 loads cover inputs at idx 1..14
            const float4* p4 = (const float4*)(x + base + (size_t)gr * IMG_W + (gc0 - 1));
            const float4* q4 = (const float4*)(y + base + (size_t)gr * IMG_W + (gc0 - 1));
            float4 a0 = p4[0], a1 = p4[1], a2 = p4[2], a3 = p4[3];
            float4 b0 = q4[0], b1 = q4[1], b2 = q4[2], b3 = q4[3];
            xin[0]=a0.x; xin[1]=a0.y; xin[2]=a0.z; xin[3]=a0.w;
            xin[4]=a1.x; xin[5]=a1.y; xin[6]=a1.z; xin[7]=a1.w;
            xin[8]=a2.x; xin[9]=a2.y; xin[10]=a2.z; xin[11]=a2.w;
            xin[12]=a3.x; xin[13]=a3.y; xin[14]=a3.z; xin[15]=a3.w;
            yin[0]=b0.x; yin[1]=b0.y; yin[2]=b0.z; yin[3]=b0.w;
            yin[4]=b1.x; yin[5]=b1.y; yin[6]=b1.z; yin[7]=b1.w;
            yin[8]=b2.x; yin[9]=b2.y; yin[10]=b2.z; yin[11]=b2.w;
            yin[12]=b3.x; yin[13]=b3.y; yin[14]=b3.z; yin[15]=b3.w;
        } else if (row_ok) {
            // column-edge tiles: scalar loads with clamp + zero-mask
            const float* prow = x + base + (size_t)gr * IMG_W;
            const float* qrow = y + base + (size_t)gr * IMG_W;
            xin[0] = 0.f; yin[0] = 0.f; xin[15] = 0.f; yin[15] = 0.f;
            #pragma unroll
            for (int j = 0; j < 14; ++j) {
                int gc = gc0 + j;
                bool ok = ((unsigned)gc < IMG_W);
                int gcc = gc < 0 ? 0 : (gc > IMG_W - 1 ? IMG_W - 1 : gc);
                float xv = prow[gcc];
                float yv = qrow[gcc];
                xin[j + 1] = ok ? xv : 0.f;
                yin[j + 1] = ok ? yv : 0.f;
            }
        } else {
            #pragma unroll
            for (int j = 0; j < 16; ++j) { xin[j] = 0.f; yin[j] = 0.f; }
        }

        float aX[8], aY[8], aZ[8], aW[8];   // hx, hy, h(x^2+y^2), h(xy)
        #pragma unroll
        for (int o = 0; o < 8; ++o) { aX[o]=0.f; aY[o]=0.f; aZ[o]=0.f; aW[o]=0.f; }

        #pragma unroll
        for (int d = 0; d < 14; ++d) {
            float xv = xin[d + 1], yv = yin[d + 1];
            float zz = fmaf(xv, xv, yv * yv);   // x^2 + y^2
            float xy = xv * yv;
            #pragma unroll
            for (int o = 0; o < 8; ++o) {
                const int t = d - o;
                if (t >= 0 && t < 7) {
                    const float gw = g[t];
                    aX[o] = fmaf(gw, xv, aX[o]);
                    aY[o] = fmaf(gw, yv, aY[o]);
                    aZ[o] = fmaf(gw, zz, aZ[o]);
                    aW[o] = fmaf(gw, xy, aW[o]);
                }
            }
        }
        // swizzled stores: col 8k+o -> position 8o+k (cpos involution)
        #pragma unroll
        for (int o = 0; o < 8; ++o) {
            hA[rr][8 * o + k] = make_float4(aX[o], aY[o], aZ[o], aW[o]);
        }
    }
    __syncthreads();

    // ---------------- Phase 2: vertical pass + SSIM ----------------
    const int c  = tid & 63;
    const int rb = (tid >> 6) * 4;   // output rows rb..rb+3
    const int pc = cpos(c);

    float4 wa[10];
    #pragma unroll
    for (int d = 0; d < 10; ++d) wa[d] = hA[rb + d][pc];

    const float c1 = 0.01f * 0.01f;
    const float c2 = 0.03f * 0.03f;
    float acc = 0.f;
    #pragma unroll
    for (int o = 0; o < 4; ++o) {
        float sx = 0.f, sy = 0.f, szz = 0.f, sxy = 0.f;
        #pragma unroll
        for (int d = 0; d < 7; ++d) {
            const float gw = g[d];
            float4 w = wa[o + d];
            sx  = fmaf(gw, w.x, sx);
            sy  = fmaf(gw, w.y, sy);
            szz = fmaf(gw, w.z, szz);
            sxy = fmaf(gw, w.w, sxy);
        }
        float mu1s = sx * sx;
        float mu2s = sy * sy;
        float mu12 = sx * sy;
        float s12  = sxy - mu12;                 // sigma12
        float ssum = szz - mu1s - mu2s;          // sigma1_sq + sigma2_sq
        float num  = fmaf(2.f, mu12, c1) * fmaf(2.f, s12, c2);
        float den  = (mu1s + mu2s + c1) * (ssum + c2);
        float rcp  = __builtin_amdgcn_rcpf(den);
        rcp = rcp * (2.f - den * rcp);           // 1 Newton step (rel err ~1e-7)
        acc = fmaf(num, rcp, acc);
    }

    // ---------------- Block reduction ----------------
    #pragma unroll
    for (int off = 32; off > 0; off >>= 1)
        acc += __shfl_down(acc, off, 64);

    const int wave = tid >> 6;
    const int lane = tid & 63;
    if (lane == 0) wsum[wave] = acc;
    __syncthreads();
    if (tid == 0) {
        float t = wsum[0] + wsum[1] + wsum[2] + wsum[3];
        partial[((size_t)blockIdx.z * 64) + blockIdx.y * 4 + blockIdx.x] = t;
    }
}

// Deterministic final reduction: single block, 1024 threads, double accumulation.
__global__ __launch_bounds__(1024) void ssim_reduce_kernel(
    const float4* __restrict__ p, float* __restrict__ out,
    int n4, double inv_count) {
    double a = 0.0;
    for (int i = threadIdx.x; i < n4; i += 1024) {
        float4 v = p[i];
        a += (double)v.x + (double)v.y + (double)v.z + (double)v.w;
    }
    #pragma unroll
    for (int off = 32; off > 0; off >>= 1)
        a += __shfl_down(a, off, 64);
    __shared__ double sd[16];
    const int wave = threadIdx.x >> 6;
    const int lane = threadIdx.x & 63;
    if (lane == 0) sd[wave] = a;
    __syncthreads();
    if (threadIdx.x == 0) {
        double t = 0.0;
        #pragma unroll
        for (int w = 0; w < 16; w++) t += sd[w];
        out[0] = (float)(t * inv_count);
    }
}

extern "C" void kernel_launch(void* const* d_in, const int* in_sizes, int n_in,
                              void* d_out, int out_size, void* d_ws, size_t ws_size,
                              hipStream_t stream) {
    const float* x = (const float*)d_in[0];
    const float* y = (const float*)d_in[1];
    float* out = (float*)d_out;
    float* partial = (float*)d_ws;

    const int total = in_sizes[0];                 // 12,582,912
    const int planes = total / (IMG_H * IMG_W);    // 192
    const int tiles_r = IMG_H / TH;                // 16
    const int tiles_c = IMG_W / TW;                // 4
    const int n_partial = planes * tiles_r * tiles_c;  // 12288

    dim3 grid(tiles_c, tiles_r, planes);
    ssim_tile_kernel<<<grid, dim3(256), 0, stream>>>(x, y, partial);

    ssim_reduce_kernel<<<1, 1024, 0, stream>>>((const float4*)partial, out,
                                               n_partial / 4, 1.0 / (double)total);
}

// Round 6
// 62.010 us; speedup vs baseline: 1.7846x; 1.7846x over previous
//
#include <hip/hip_runtime.h>

#define IMG_H 256
#define IMG_W 256
#define TW 64
#define TH 16
#define SR 22            // stage rows (TH + 6)
#define SC 72            // stage cols: global cols c0-4 .. c0+67 (covers needed -3..66)
#define NPAIR 36         // SC/2
#define STAGE_TASKS (SR * NPAIR)   // 792

// per-row low-3-bit rotation: uniform bank-granule spread (R4-validated model)
// for b128 writes (lanes=consecutive c, fixed row) AND b128 reads
// (lanes span 4 rows x 16 col-groups).
__device__ __forceinline__ int rotc(int r, int c) { return (c & ~7) | ((c + r) & 7); }

// Gaussian 7-tap, f64-derived f32 constants (matches numpy f32 recipe to ~1e-7 rel)
#define G0 0.03663285f
#define G1 0.11128076f
#define G2 0.21674532f
#define G3 0.27068216f

// Fused SSIM, coalesced-stage topology (R2-proven) + 4-field algebra + packed planes:
//  stage:    coalesced b64 loads of x,y -> interleaved float2 LDS tile [22][72]
//  vertical: 288 tasks, 10 shared taps -> 4 out-rows; fields (x, y, x^2+y^2, xy)
//            packed as float4 into vs[16][72] at rot-swizzled columns
//  horizontal: 1 thread = 1 out-row x 4 cols; 10 b128 reads, tap-sharing;
//            SSIM map; block reduction.
__global__ __launch_bounds__(256) void ssim_tile_kernel(
    const float* __restrict__ x, const float* __restrict__ y,
    float* __restrict__ partial) {
    __shared__ float2 sxy[SR][SC];   // (x,y) interleaved, 12.7 KB
    __shared__ float4 vs[TH][SC];    // (hx,hy,hzz,hxy), rot-swizzled cols, 18.4 KB
    __shared__ float  wsum[4];

    const int tid = threadIdx.x;
    const int bx = blockIdx.x, by = blockIdx.y, plane = blockIdx.z;
    const int r0 = by * TH, c0 = bx * TW;
    const size_t base = (size_t)plane * (IMG_H * IMG_W);
    const float g[7] = {G0, G1, G2, G3, G2, G1, G0};

    const bool interior = (bx > 0) & (bx < 3);

    // ---------------- Stage: coalesced global -> LDS ----------------
    for (int i = tid; i < STAGE_TASKS; i += 256) {
        const int rr = i / NPAIR;          // 0..21
        const int pp = i - rr * NPAIR;     // pair 0..35
        const int gr = r0 - 3 + rr;
        const int gc = c0 - 4 + 2 * pp;    // even -> 8B-aligned
        float x0 = 0.f, x1 = 0.f, y0 = 0.f, y1 = 0.f;
        if ((unsigned)gr < IMG_H) {
            const float* prow = x + base + (size_t)gr * IMG_W;
            const float* qrow = y + base + (size_t)gr * IMG_W;
            if (interior) {
                float2 xv = *(const float2*)(prow + gc);
                float2 yv = *(const float2*)(qrow + gc);
                x0 = xv.x; x1 = xv.y; y0 = yv.x; y1 = yv.y;
            } else {
                const int a0 = gc, a1 = gc + 1;
                const int c0c = a0 < 0 ? 0 : (a0 > IMG_W - 1 ? IMG_W - 1 : a0);
                const int c1c = a1 < 0 ? 0 : (a1 > IMG_W - 1 ? IMG_W - 1 : a1);
                const bool ok0 = (unsigned)a0 < IMG_W;
                const bool ok1 = (unsigned)a1 < IMG_W;
                x0 = ok0 ? prow[c0c] : 0.f;
                x1 = ok1 ? prow[c1c] : 0.f;
                y0 = ok0 ? qrow[c0c] : 0.f;
                y1 = ok1 ? qrow[c1c] : 0.f;
            }
        }
        // b128 write: (x0,y0,x1,y1) = cols 2pp, 2pp+1 interleaved
        *(float4*)&sxy[rr][2 * pp] = make_float4(x0, y0, x1, y1);
    }
    __syncthreads();

    // ---------------- Vertical pass: 288 tasks (a = row-group, c = col) ----------------
    for (int i = tid; i < 4 * SC; i += 256) {
        const int a = i / SC;        // 0..3
        const int c = i - a * SC;    // 0..71
        float aX[4] = {0,0,0,0}, aY[4] = {0,0,0,0};
        float aZ[4] = {0,0,0,0}, aW[4] = {0,0,0,0};
        #pragma unroll
        for (int t = 0; t < 10; ++t) {
            float2 v = sxy[4 * a + t][c];
            const float xv = v.x, yv = v.y;
            const float zz = fmaf(xv, xv, yv * yv);
            const float xy = xv * yv;
            #pragma unroll
            for (int o = 0; o < 4; ++o) {
                const int dy = t - o;
                if (dy >= 0 && dy < 7) {
                    const float gw = g[dy];
                    aX[o] = fmaf(gw, xv, aX[o]);
                    aY[o] = fmaf(gw, yv, aY[o]);
                    aZ[o] = fmaf(gw, zz, aZ[o]);
                    aW[o] = fmaf(gw, xy, aW[o]);
                }
            }
        }
        #pragma unroll
        for (int o = 0; o < 4; ++o) {
            const int R = 4 * a + o;
            vs[R][rotc(R, c)] = make_float4(aX[o], aY[o], aZ[o], aW[o]);
        }
    }
    __syncthreads();

    // ---------------- Horizontal pass + SSIM ----------------
    // lane -> (out-row R, col-group m): residues (4m+j+1+R)&7 = (lane&7)+const
    // per read instr -> uniform 8 lanes/granule (conflict-free, R4-validated).
    const int R = 4 * (tid >> 6) + (tid & 3);
    const int m = (tid >> 2) & 15;       // cols 4m..4m+3

    float4 wv[10];
    #pragma unroll
    for (int j = 0; j < 10; ++j)
        wv[j] = vs[R][rotc(R, 4 * m + j + 1)];   // vs col cc = actual col cc-4

    const float c1 = 0.01f * 0.01f;
    const float c2 = 0.03f * 0.03f;
    float acc = 0.f;
    #pragma unroll
    for (int o = 0; o < 4; ++o) {
        float sx = 0.f, sy = 0.f, szz = 0.f, sxy2 = 0.f;
        #pragma unroll
        for (int dx = 0; dx < 7; ++dx) {
            const float gw = g[dx];
            float4 w = wv[o + dx];
            sx   = fmaf(gw, w.x, sx);
            sy   = fmaf(gw, w.y, sy);
            szz  = fmaf(gw, w.z, szz);
            sxy2 = fmaf(gw, w.w, sxy2);
        }
        const float mu1s = sx * sx;
        const float mu2s = sy * sy;
        const float mu12 = sx * sy;
        const float s12  = sxy2 - mu12;          // sigma12
        const float ssum = szz - mu1s - mu2s;    // sigma1_sq + sigma2_sq
        const float num  = fmaf(2.f, mu12, c1) * fmaf(2.f, s12, c2);
        const float den  = (mu1s + mu2s + c1) * (ssum + c2);
        float rcp = __builtin_amdgcn_rcpf(den);
        rcp = rcp * (2.f - den * rcp);           // 1 Newton step (rel err ~1e-7)
        acc = fmaf(num, rcp, acc);
    }

    // ---------------- Block reduction ----------------
    #pragma unroll
    for (int off = 32; off > 0; off >>= 1)
        acc += __shfl_down(acc, off, 64);

    const int wave = tid >> 6;
    const int lane = tid & 63;
    if (lane == 0) wsum[wave] = acc;
    __syncthreads();
    if (tid == 0) {
        float t = wsum[0] + wsum[1] + wsum[2] + wsum[3];
        partial[((size_t)blockIdx.z * 64) + blockIdx.y * 4 + blockIdx.x] = t;
    }
}

// Deterministic final reduction: single block, 1024 threads, double accumulation.
__global__ __launch_bounds__(1024) void ssim_reduce_kernel(
    const float4* __restrict__ p, float* __restrict__ out,
    int n4, double inv_count) {
    double a = 0.0;
    for (int i = threadIdx.x; i < n4; i += 1024) {
        float4 v = p[i];
        a += (double)v.x + (double)v.y + (double)v.z + (double)v.w;
    }
    #pragma unroll
    for (int off = 32; off > 0; off >>= 1)
        a += __shfl_down(a, off, 64);
    __shared__ double sd[16];
    const int wave = threadIdx.x >> 6;
    const int lane = threadIdx.x & 63;
    if (lane == 0) sd[wave] = a;
    __syncthreads();
    if (threadIdx.x == 0) {
        double t = 0.0;
        #pragma unroll
        for (int w = 0; w < 16; w++) t += sd[w];
        out[0] = (float)(t * inv_count);
    }
}

extern "C" void kernel_launch(void* const* d_in, const int* in_sizes, int n_in,
                              void* d_out, int out_size, void* d_ws, size_t ws_size,
                              hipStream_t stream) {
    const float* x = (const float*)d_in[0];
    const float* y = (const float*)d_in[1];
    float* out = (float*)d_out;
    float* partial = (float*)d_ws;

    const int total = in_sizes[0];                 // 12,582,912
    const int planes = total / (IMG_H * IMG_W);    // 192
    const int tiles_r = IMG_H / TH;                // 16
    const int tiles_c = IMG_W / TW;                // 4
    const int n_partial = planes * tiles_r * tiles_c;  // 12288

    dim3 grid(tiles_c, tiles_r, planes);
    ssim_tile_kernel<<<grid, dim3(256), 0, stream>>>(x, y, partial);

    ssim_reduce_kernel<<<1, 1024, 0, stream>>>((const float4*)partial, out,
                                               n_partial / 4, 1.0 / (double)total);
}

// Round 7
// 48.892 us; speedup vs baseline: 2.2634x; 1.2683x over previous
//
#include <hip/hip_runtime.h>

#define IMG_H 256
#define IMG_W 256
#define TW 64
#define TH 16
#define SC 72            // vertical-task cols: global cols c0-4 .. c0+67 (need -3..66)

// per-row low-3-bit rotation: uniform bank-granule spread for b128 writes and
// reads. Validated R6: SQ_LDS_BANK_CONFLICT 245K (~zero).
__device__ __forceinline__ int rotc(int r, int c) { return (c & ~7) | ((c + r) & 7); }

// Gaussian 7-tap, f64-derived f32 constants (matches numpy f32 recipe to ~1e-7 rel)
#define G0 0.03663285f
#define G1 0.11128076f
#define G2 0.21674532f
#define G3 0.27068216f

// Fused SSIM, two-phase (stage phase deleted — R7):
//  vertical:  288 tasks (4 row-groups x 72 cols) read x,y DIRECTLY from global
//             (lane=col -> coalesced; halo re-reads hit L1/L2). 10 shared taps
//             -> 4 out-rows; fields (x, y, x^2+y^2, x*y) packed as float4 into
//             vs[16][72] at rot-swizzled columns.
//  horizontal: 1 thread = 1 out-row x 4 cols; 10 b128 reads, tap-sharing;
//             SSIM map; block reduction.  One barrier total.
__global__ __launch_bounds__(256) void ssim_tile_kernel(
    const float* __restrict__ x, const float* __restrict__ y,
    float* __restrict__ partial) {
    __shared__ float4 vs[TH][SC];    // 18432 B -> 8 blocks/CU
    __shared__ float  wsum[4];

    const int tid = threadIdx.x;
    const int bx = blockIdx.x, by = blockIdx.y, plane = blockIdx.z;
    const int r0 = by * TH, c0 = bx * TW;
    const size_t base = (size_t)plane * (IMG_H * IMG_W);
    const float g[7] = {G0, G1, G2, G3, G2, G1, G0};

    // ---------------- Vertical pass: global -> registers -> vs ----------------
    for (int i = tid; i < 4 * SC; i += 256) {
        const int a = i / SC;        // row-group 0..3
        const int c = i - a * SC;    // 0..71
        const int gc = c0 - 4 + c;
        // column predicate/clamp hoisted: fixed for all 20 loads of this task
        const bool ok_c = ((unsigned)gc < IMG_W);
        const int  gcc  = gc < 0 ? 0 : (gc > IMG_W - 1 ? IMG_W - 1 : gc);
        const int  rstart = r0 - 3 + 4 * a;

        float aX[4] = {0,0,0,0}, aY[4] = {0,0,0,0};
        float aZ[4] = {0,0,0,0}, aW[4] = {0,0,0,0};
        #pragma unroll
        for (int t = 0; t < 10; ++t) {
            const int gr  = rstart + t;
            const bool ok = ok_c & ((unsigned)gr < IMG_H);
            const int grc = gr < 0 ? 0 : (gr > IMG_H - 1 ? IMG_H - 1 : gr);
            const size_t idx = base + ((size_t)grc << 8) + gcc;  // always in-bounds
            float xv = x[idx];
            float yv = y[idx];
            xv = ok ? xv : 0.f;
            yv = ok ? yv : 0.f;
            const float zz = fmaf(xv, xv, yv * yv);
            const float xy = xv * yv;
            #pragma unroll
            for (int o = 0; o < 4; ++o) {
                const int dy = t - o;
                if (dy >= 0 && dy < 7) {
                    const float gw = g[dy];
                    aX[o] = fmaf(gw, xv, aX[o]);
                    aY[o] = fmaf(gw, yv, aY[o]);
                    aZ[o] = fmaf(gw, zz, aZ[o]);
                    aW[o] = fmaf(gw, xy, aW[o]);
                }
            }
        }
        #pragma unroll
        for (int o = 0; o < 4; ++o) {
            const int R = 4 * a + o;
            vs[R][rotc(R, c)] = make_float4(aX[o], aY[o], aZ[o], aW[o]);
        }
    }
    __syncthreads();

    // ---------------- Horizontal pass + SSIM ----------------
    // lane -> (out-row R, col-group m): conflict-free b128 reads (R6-validated)
    const int R = 4 * (tid >> 6) + (tid & 3);
    const int m = (tid >> 2) & 15;       // cols 4m..4m+3

    float4 wv[10];
    #pragma unroll
    for (int j = 0; j < 10; ++j)
        wv[j] = vs[R][rotc(R, 4 * m + j + 1)];   // vs col cc = actual col cc-4

    const float c1 = 0.01f * 0.01f;
    const float c2 = 0.03f * 0.03f;
    float acc = 0.f;
    #pragma unroll
    for (int o = 0; o < 4; ++o) {
        float sx = 0.f, sy = 0.f, szz = 0.f, sxy2 = 0.f;
        #pragma unroll
        for (int dx = 0; dx < 7; ++dx) {
            const float gw = g[dx];
            float4 w = wv[o + dx];
            sx   = fmaf(gw, w.x, sx);
            sy   = fmaf(gw, w.y, sy);
            szz  = fmaf(gw, w.z, szz);
            sxy2 = fmaf(gw, w.w, sxy2);
        }
        const float mu1s = sx * sx;
        const float mu2s = sy * sy;
        const float mu12 = sx * sy;
        const float s12  = sxy2 - mu12;          // sigma12
        const float ssum = szz - mu1s - mu2s;    // sigma1_sq + sigma2_sq
        const float num  = fmaf(2.f, mu12, c1) * fmaf(2.f, s12, c2);
        const float den  = (mu1s + mu2s + c1) * (ssum + c2);
        float rcp = __builtin_amdgcn_rcpf(den);
        rcp = rcp * (2.f - den * rcp);           // 1 Newton step (rel err ~1e-7)
        acc = fmaf(num, rcp, acc);
    }

    // ---------------- Block reduction ----------------
    #pragma unroll
    for (int off = 32; off > 0; off >>= 1)
        acc += __shfl_down(acc, off, 64);

    const int wave = tid >> 6;
    const int lane = tid & 63;
    if (lane == 0) wsum[wave] = acc;
    __syncthreads();
    if (tid == 0) {
        float t = wsum[0] + wsum[1] + wsum[2] + wsum[3];
        partial[((size_t)blockIdx.z * 64) + blockIdx.y * 4 + blockIdx.x] = t;
    }
}

// Deterministic final reduction: single block, 1024 threads, double accumulation.
__global__ __launch_bounds__(1024) void ssim_reduce_kernel(
    const float4* __restrict__ p, float* __restrict__ out,
    int n4, double inv_count) {
    double a = 0.0;
    for (int i = threadIdx.x; i < n4; i += 1024) {
        float4 v = p[i];
        a += (double)v.x + (double)v.y + (double)v.z + (double)v.w;
    }
    #pragma unroll
    for (int off = 32; off > 0; off >>= 1)
        a += __shfl_down(a, off, 64);
    __shared__ double sd[16];
    const int wave = threadIdx.x >> 6;
    const int lane = threadIdx.x & 63;
    if (lane == 0) sd[wave] = a;
    __syncthreads();
    if (threadIdx.x == 0) {
        double t = 0.0;
        #pragma unroll
        for (int w = 0; w < 16; w++) t += sd[w];
        out[0] = (float)(t * inv_count);
    }
}

extern "C" void kernel_launch(void* const* d_in, const int* in_sizes, int n_in,
                              void* d_out, int out_size, void* d_ws, size_t ws_size,
                              hipStream_t stream) {
    const float* x = (const float*)d_in[0];
    const float* y = (const float*)d_in[1];
    float* out = (float*)d_out;
    float* partial = (float*)d_ws;

    const int total = in_sizes[0];                 // 12,582,912
    const int planes = total / (IMG_H * IMG_W);    // 192
    const int tiles_r = IMG_H / TH;                // 16
    const int tiles_c = IMG_W / TW;                // 4
    const int n_partial = planes * tiles_r * tiles_c;  // 12288

    dim3 grid(tiles_c, tiles_r, planes);
    ssim_tile_kernel<<<grid, dim3(256), 0, stream>>>(x, y, partial);

    ssim_reduce_kernel<<<1, 1024, 0, stream>>>((const float4*)partial, out,
                                               n_partial / 4, 1.0 / (double)total);
}

// Round 8
// 45.519 us; speedup vs baseline: 2.4311x; 1.0741x over previous
//
#include <hip/hip_runtime.h>

#define IMG_H 256
#define IMG_W 256
#define TW 64
#define TH 16
#define SC 72            // vertical-task cols: global cols c0-4 .. c0+67 (need -3..66)

typedef float v2f __attribute__((ext_vector_type(2)));

// per-row low-3-bit rotation: uniform bank-granule spread for b128 writes and
// reads. Validated R6/R7: SQ_LDS_BANK_CONFLICT ~0.
__device__ __forceinline__ int rotc(int r, int c) { return (c & ~7) | ((c + r) & 7); }

// Gaussian 7-tap, f64-derived f32 constants (matches numpy f32 recipe to ~1e-7 rel)
#define G0 0.03663285f
#define G1 0.11128076f
#define G2 0.21674532f
#define G3 0.27068216f

// Fused SSIM, two-phase, packed-f32 math (R8):
//  vertical:  288 tasks (4 row-groups x 72 cols) read x,y directly from global
//             (coalesced; halo re-reads are L1/L2 hits — R7-validated). Fields
//             packed as pairs (x,y) and (x^2+y^2, x*y) -> v_pk_fma_f32: 2 inst
//             per tap-output instead of 4. Interior blocks (44%) take a
//             clamp-free load path with compile-time row offsets.
//  horizontal: 1 thread = 1 out-row x 4 cols; 10 b128 reads; packed 7-tap;
//             SSIM map; block reduction. One barrier total.
__global__ __launch_bounds__(256) void ssim_tile_kernel(
    const float* __restrict__ x, const float* __restrict__ y,
    float* __restrict__ partial) {
    __shared__ float4 vs[TH][SC];    // 18432 B -> 8 blocks/CU (LDS-capped)
    __shared__ float  wsum[4];

    const int tid = threadIdx.x;
    const int bx = blockIdx.x, by = blockIdx.y, plane = blockIdx.z;
    const int r0 = by * TH, c0 = bx * TW;
    const size_t base = (size_t)plane * (IMG_H * IMG_W);
    const float g[7] = {G0, G1, G2, G3, G2, G1, G0};

    v2f g2[7];
    #pragma unroll
    for (int d = 0; d < 7; ++d) { g2[d].x = g[d]; g2[d].y = g[d]; }

    // uniform per-block: all vertical-task loads in-bounds?
    const bool fast = ((bx == 1) | (bx == 2)) & (by >= 1) & (by <= 14);

    // ---------------- Vertical pass: global -> registers -> vs ----------------
    auto vtask = [&](int a, int c) {
        const int gc = c0 - 4 + c;
        const int rstart = r0 - 3 + 4 * a;

        float xr[10], yr[10];
        if (fast) {
            // all in-bounds: constant row offsets, no clamps/selects
            const float* px = x + base + (size_t)rstart * IMG_W + gc;
            const float* py = y + base + (size_t)rstart * IMG_W + gc;
            #pragma unroll
            for (int t = 0; t < 10; ++t) {
                xr[t] = px[t * IMG_W];
                yr[t] = py[t * IMG_W];
            }
        } else {
            const bool ok_c = ((unsigned)gc < IMG_W);
            const int  gcc  = gc < 0 ? 0 : (gc > IMG_W - 1 ? IMG_W - 1 : gc);
            #pragma unroll
            for (int t = 0; t < 10; ++t) {
                const int gr  = rstart + t;
                const bool ok = ok_c & ((unsigned)gr < IMG_H);
                const int grc = gr < 0 ? 0 : (gr > IMG_H - 1 ? IMG_H - 1 : gr);
                const size_t idx = base + ((size_t)grc << 8) + gcc;
                float xv = x[idx], yv = y[idx];
                xr[t] = ok ? xv : 0.f;
                yr[t] = ok ? yv : 0.f;
            }
        }

        v2f aA[4], aB[4];
        #pragma unroll
        for (int o = 0; o < 4; ++o) { aA[o] = (v2f)0.f; aB[o] = (v2f)0.f; }

        #pragma unroll
        for (int t = 0; t < 10; ++t) {
            const float xv = xr[t], yv = yr[t];
            v2f ina; ina.x = xv; ina.y = yv;
            v2f inb; inb.x = fmaf(xv, xv, yv * yv); inb.y = xv * yv;
            #pragma unroll
            for (int o = 0; o < 4; ++o) {
                const int dy = t - o;
                if (dy >= 0 && dy < 7) {
                    aA[o] = __builtin_elementwise_fma(g2[dy], ina, aA[o]);
                    aB[o] = __builtin_elementwise_fma(g2[dy], inb, aB[o]);
                }
            }
        }
        #pragma unroll
        for (int o = 0; o < 4; ++o) {
            const int R = 4 * a + o;
            vs[R][rotc(R, c)] = make_float4(aA[o].x, aA[o].y, aB[o].x, aB[o].y);
        }
    };

    vtask(tid >> 6, tid & 63);                    // tasks (a, c=0..63)
    if (tid < 32) vtask(tid >> 3, 64 + (tid & 7)); // tasks (a, c=64..71), wave 0

    __syncthreads();

    // ---------------- Horizontal pass + SSIM ----------------
    const int R = 4 * (tid >> 6) + (tid & 3);
    const int m = (tid >> 2) & 15;       // cols 4m..4m+3

    v2f wa[10], wb[10];
    #pragma unroll
    for (int j = 0; j < 10; ++j) {
        float4 w = vs[R][rotc(R, 4 * m + j + 1)];   // vs col cc = actual col cc-4
        wa[j].x = w.x; wa[j].y = w.y;
        wb[j].x = w.z; wb[j].y = w.w;
    }

    const float c1 = 0.01f * 0.01f;
    const float c2 = 0.03f * 0.03f;
    float acc = 0.f;
    #pragma unroll
    for (int o = 0; o < 4; ++o) {
        v2f sab = (v2f)0.f, szw = (v2f)0.f;
        #pragma unroll
        for (int dx = 0; dx < 7; ++dx) {
            sab = __builtin_elementwise_fma(g2[dx], wa[o + dx], sab);
            szw = __builtin_elementwise_fma(g2[dx], wb[o + dx], szw);
        }
        const float sx = sab.x, sy = sab.y, szz = szw.x, sxy2 = szw.y;
        const float mu1s = sx * sx;
        const float mu2s = sy * sy;
        const float mu12 = sx * sy;
        const float s12  = sxy2 - mu12;          // sigma12
        const float ssum = szz - mu1s - mu2s;    // sigma1_sq + sigma2_sq
        const float num  = fmaf(2.f, mu12, c1) * fmaf(2.f, s12, c2);
        const float den  = (mu1s + mu2s + c1) * (ssum + c2);
        float rcp = __builtin_amdgcn_rcpf(den);
        rcp = rcp * (2.f - den * rcp);           // 1 Newton step (rel err ~1e-7)
        acc = fmaf(num, rcp, acc);
    }

    // ---------------- Block reduction ----------------
    #pragma unroll
    for (int off = 32; off > 0; off >>= 1)
        acc += __shfl_down(acc, off, 64);

    const int wave = tid >> 6;
    const int lane = tid & 63;
    if (lane == 0) wsum[wave] = acc;
    __syncthreads();
    if (tid == 0) {
        float t = wsum[0] + wsum[1] + wsum[2] + wsum[3];
        partial[((size_t)blockIdx.z * 64) + blockIdx.y * 4 + blockIdx.x] = t;
    }
}

// Deterministic final reduction: single block, 1024 threads, double accumulation.
__global__ __launch_bounds__(1024) void ssim_reduce_kernel(
    const float4* __restrict__ p, float* __restrict__ out,
    int n4, double inv_count) {
    double a = 0.0;
    for (int i = threadIdx.x; i < n4; i += 1024) {
        float4 v = p[i];
        a += (double)v.x + (double)v.y + (double)v.z + (double)v.w;
    }
    #pragma unroll
    for (int off = 32; off > 0; off >>= 1)
        a += __shfl_down(a, off, 64);
    __shared__ double sd[16];
    const int wave = threadIdx.x >> 6;
    const int lane = threadIdx.x & 63;
    if (lane == 0) sd[wave] = a;
    __syncthreads();
    if (threadIdx.x == 0) {
        double t = 0.0;
        #pragma unroll
        for (int w = 0; w < 16; w++) t += sd[w];
        out[0] = (float)(t * inv_count);
    }
}

extern "C" void kernel_launch(void* const* d_in, const int* in_sizes, int n_in,
                              void* d_out, int out_size, void* d_ws, size_t ws_size,
                              hipStream_t stream) {
    const float* x = (const float*)d_in[0];
    const float* y = (const float*)d_in[1];
    float* out = (float*)d_out;
    float* partial = (float*)d_ws;

    const int total = in_sizes[0];                 // 12,582,912
    const int planes = total / (IMG_H * IMG_W);    // 192
    const int tiles_r = IMG_H / TH;                // 16
    const int tiles_c = IMG_W / TW;                // 4
    const int n_partial = planes * tiles_r * tiles_c;  // 12288

    dim3 grid(tiles_c, tiles_r, planes);
    ssim_tile_kernel<<<grid, dim3(256), 0, stream>>>(x, y, partial);

    ssim_reduce_kernel<<<1, 1024, 0, stream>>>((const float4*)partial, out,
                                               n_partial / 4, 1.0 / (double)total);
}